// Round 7
// baseline (819.361 us; speedup 1.0000x reference)
//
#include <hip/hip_runtime.h>
#include <math.h>

#define D_OPT   128
#define N_SIM   2048
#define M_STEPS 64
#define HID     64

// Round 13: phase-mixed double-set schedule.
// Falsified so far: TLP (R9b +29% occ -> -5% time), barrier vmcnt drain
// (R11 flat), intra-phase ILP (R12 2x ladders -> flat). Remaining theory:
// phase ALTERNATION (all-MFMA segment, barrier, all-VALU/trans segment)
// leaves each pipe idle half the time, and lockstep waves can't complement.
// R13: two element-sets per block (A=0..63, B=64..127), phase-offset by a
// half-step:  [ladder_B(s) || update_A(s)] bar [ladder_A(s+1) || update_B(s)] bar
// Every segment = one full MFMA ladder + one full update phase, independent,
// freely interleavable. Same per-wave work and element count as R12 -> the
// only delta vs R12 is the interleave. Race audit: pkx/nvp single-buffered
// per set; every producer->consumer pair crosses exactly one barrier.
// Pipeline (validated): L1 = mfma 16x16x16f16 (bias k-slot 3 x packed 1.0);
// L2 = 2x mfma 16x16x32 (baked k-permutation); L3 = 2x mfma, w3 row 0.

typedef _Float16 f16x8 __attribute__((ext_vector_type(8)));
typedef _Float16 f16x4 __attribute__((ext_vector_type(4)));
typedef _Float16 f16x2 __attribute__((ext_vector_type(2)));
typedef float    f32x4 __attribute__((ext_vector_type(4)));
typedef unsigned int u32;
typedef u32 u32x2 __attribute__((ext_vector_type(2)));
typedef u32 u32x4 __attribute__((ext_vector_type(4)));

__device__ __forceinline__ u32 pk2u(float a, float b) {
#if __has_builtin(__builtin_amdgcn_cvt_pkrtz)
    return __builtin_bit_cast(u32, __builtin_amdgcn_cvt_pkrtz(a, b));
#else
    f16x2 p; p[0] = (_Float16)a; p[1] = (_Float16)b;
    return __builtin_bit_cast(u32, p);
#endif
}

__device__ __forceinline__ u32 pk_relu_cvt(float a, float b) {
    f16x2 p = __builtin_bit_cast(f16x2, pk2u(a, b));
    const f16x2 z = { (_Float16)0.0f, (_Float16)0.0f };
#if __has_builtin(__builtin_elementwise_max)
    p = __builtin_elementwise_max(p, z);
#else
    p[0] = p[0] > z[0] ? p[0] : z[0];
    p[1] = p[1] > z[1] ? p[1] : z[1];
#endif
    return __builtin_bit_cast(u32, p);
}

// one full MFMA ladder for 4 mt tiles of a set (wave==net)
#define LADDER(PKXW, NVPW)                                                    \
  do {                                                                        \
    _Pragma("unroll 2")                                                       \
    for (int mt = 0; mt < 4; ++mt) {                                          \
      const u32x2 pksv = (PKXW)[mt * 16 + mA];                                \
      const f16x4 B1f = __builtin_bit_cast(f16x4, pksv);                      \
      u32x4 b2u[2];                                                           \
      _Pragma("unroll")                                                       \
      for (int t = 0; t < 4; ++t) {                                           \
        const f32x4 acc = __builtin_amdgcn_mfma_f32_16x16x16f16(              \
            A1[t], B1f, zc, 0, 0, 0);                                         \
        b2u[t >> 1][(t & 1) * 2 + 0] = pk_relu_cvt(acc[0], acc[1]);           \
        b2u[t >> 1][(t & 1) * 2 + 1] = pk_relu_cvt(acc[2], acc[3]);           \
      }                                                                       \
      const f16x8 B2f0 = __builtin_bit_cast(f16x8, b2u[0]);                   \
      const f16x8 B2f1 = __builtin_bit_cast(f16x8, b2u[1]);                   \
      u32x4 b3u[2];                                                           \
      _Pragma("unroll")                                                       \
      for (int gt = 0; gt < 4; ++gt) {                                        \
        f32x4 acc = __builtin_amdgcn_mfma_f32_16x16x32_f16(                   \
            A2[gt][0], B2f0, cinit2[gt], 0, 0, 0);                            \
        acc = __builtin_amdgcn_mfma_f32_16x16x32_f16(                         \
            A2[gt][1], B2f1, acc, 0, 0, 0);                                   \
        b3u[gt >> 1][(gt & 1) * 2 + 0] = pk_relu_cvt(acc[0], acc[1]);         \
        b3u[gt >> 1][(gt & 1) * 2 + 1] = pk_relu_cvt(acc[2], acc[3]);         \
      }                                                                       \
      f32x4 acc3 = __builtin_amdgcn_mfma_f32_16x16x32_f16(                    \
          A3[0], __builtin_bit_cast(f16x8, b3u[0]), zc, 0, 0, 0);             \
      acc3 = __builtin_amdgcn_mfma_f32_16x16x32_f16(                          \
          A3[1], __builtin_bit_cast(f16x8, b3u[1]), acc3, 0, 0, 0);           \
      if (q == 0) (NVPW)[mt * 16 + mA] = acc3[0];                             \
    }                                                                         \
  } while (0)

// once-per-lane SDE update of the owned element of a set
#define UPDATE(NVPX, Sr, Vr, z1c, z2c, z1n, z2n, dtx, sdtx, PKXW, snext)      \
  do {                                                                        \
    const float o0 = (NVPX)[0][lane] + b3n0;                                  \
    const float o1 = (NVPX)[1][lane] + b3n1;                                  \
    const float o2 = (NVPX)[2][lane] + b3n2;                                  \
    const float o3 = (NVPX)[3][lane] + b3n3;                                  \
    const float e0 = __expf(2.0f * o0);                                       \
    const float e1 = __expf(2.0f * o1);                                       \
    const float e2 = __expf(2.0f * o2);                                       \
    const float e3 = __expf(2.0f * o3);                                       \
    const float N0 = 1.0f - 2.0f / (e0 + 1.0f);                               \
    const float N1 = 1.0f - 2.0f / (e1 + 1.0f);                               \
    const float N2 = 1.0f - 2.0f / (e2 + 1.0f);                               \
    const float N3 = 1.0f - 2.0f / (e3 + 1.0f);                               \
    const float zz2 = fmaf(rho, z1c, rho_c * z2c);                            \
    const float fS = fmaf(N1 * sdtx, z1c, N0 * dtx);                          \
    const float fV = fmaf(N3 * sdtx, zz2, N2 * dtx);                          \
    Sr = fmaf(Sr, fS, Sr);                                                    \
    Vr = fmaf(Vr, fV, Vr);                                                    \
    u32x2 pkn;                                                                \
    pkn[0] = pk2u(Sr, Vr);                                                    \
    pkn[1] = pk2u(dtx * (float)(snext), 1.0f);                                \
    (PKXW)[lane] = pkn;                                                       \
    z1c = z1n; z2c = z2n;                                                     \
  } while (0)

// lgkm-only barrier (validated R11/R12): DS writes drained, vmcnt in flight
#define LBAR()                                                                \
  do {                                                                        \
    __builtin_amdgcn_sched_barrier(0);                                        \
    asm volatile("s_waitcnt lgkmcnt(0)\n\ts_barrier" ::: "memory");           \
    __builtin_amdgcn_sched_barrier(0);                                        \
  } while (0)

__global__ __launch_bounds__(256, 4) void nsde_kernel(
    const float* __restrict__ S0p, const float* __restrict__ Kp,
    const float* __restrict__ Tp,  const float* __restrict__ rfp,
    const float* __restrict__ V0p, const float* __restrict__ rhop,
    const float* __restrict__ Z1,  const float* __restrict__ Z2r,
    const float* __restrict__ W1,  const float* __restrict__ B1,
    const float* __restrict__ W2,  const float* __restrict__ B2,
    const float* __restrict__ W3,  const float* __restrict__ B3,
    float* __restrict__ out)
{
    __shared__ float nvpA[4][64], nvpB[4][64];   // [net][element], 2 KB
    __shared__ u32x2 pkxA[4][64], pkxB[4][64];   // [wave][element], 4 KB

    const int tid  = threadIdx.x;
    const int wave = tid >> 6;        // wave == net
    const int lane = tid & 63;
    const int q    = lane >> 4;
    const int mA   = lane & 15;
    const float rf = rfp[0];

    const float* w1g = W1 + wave * 256;   // [4][64]
    const float* b1g = B1 + wave * 64;
    const float* w2g = W2 + wave * 4096;  // [64][64] (h, g)
    const float* b2g = B2 + wave * 64;
    const float* w3g = W3 + wave * 64;    // [64]

    // ---------------- constant fragments (register-resident) ----------------
    f16x4 A1[4];
    #pragma unroll
    for (int t = 0; t < 4; ++t) {
        f16x4 a = { (_Float16)0.0f, (_Float16)0.0f, (_Float16)0.0f, (_Float16)0.0f };
        if (q == 0) {
            const int h = t * 16 + mA;
            a[0] = (_Float16)w1g[0 * 64 + h];
            a[1] = (_Float16)w1g[1 * 64 + h];
            a[2] = (_Float16)w1g[3 * 64 + h];
            a[3] = (_Float16)fmaf(rf, w1g[2 * 64 + h], b1g[h]);
        }
        A1[t] = a;
    }

    f16x8 A2[4][2];
    #pragma unroll
    for (int gt = 0; gt < 4; ++gt)
        #pragma unroll
        for (int kt = 0; kt < 2; ++kt) {
            f16x8 a;
            #pragma unroll
            for (int j = 0; j < 8; ++j) {
                const int h1 = (2 * kt + (j >> 2)) * 16 + 4 * q + (j & 3);
                a[j] = (_Float16)w2g[h1 * 64 + gt * 16 + mA];
            }
            A2[gt][kt] = a;
        }

    f16x8 A3[2];
    #pragma unroll
    for (int kt = 0; kt < 2; ++kt) {
        f16x8 a;
        #pragma unroll
        for (int j = 0; j < 8; ++j) a[j] = (_Float16)0.0f;
        if (mA == 0) {
            #pragma unroll
            for (int j = 0; j < 8; ++j) {
                const int g = (2 * kt + (j >> 2)) * 16 + 4 * q + (j & 3);
                a[j] = (_Float16)w3g[g];
            }
        }
        A3[kt] = a;
    }

    f32x4 cinit2[4];
    #pragma unroll
    for (int t = 0; t < 4; ++t)
        #pragma unroll
        for (int r = 0; r < 4; ++r)
            cinit2[t][r] = b2g[t * 16 + 4 * q + r];
    const f32x4 zc = { 0.0f, 0.0f, 0.0f, 0.0f };

    const float b3n0 = B3[0], b3n1 = B3[1], b3n2 = B3[2], b3n3 = B3[3];

    // ---------------- per-element state (sets A and B) ----------------
    const int ebase = blockIdx.x * 128;
    const int dA_ = (ebase + lane) & (D_OPT - 1);
    const int dB_ = (ebase + 64 + lane) & (D_OPT - 1);
    const float dtA  = Tp[dA_] * (1.0f / (float)M_STEPS);
    const float dtB  = Tp[dB_] * (1.0f / (float)M_STEPS);
    const float sdtA = sqrtf(dtA);
    const float sdtB = sqrtf(dtB);

    float SregA = S0p[dA_], SregB = S0p[dB_];
    float VregA = V0p[0],   VregB = V0p[0];
    {
        u32x2 pk0;
        pk0[0] = pk2u(SregA, VregA);
        pk0[1] = pk2u(0.0f, 1.0f);
        pkxA[wave][lane] = pk0;
        u32x2 pk1;
        pk1[0] = pk2u(SregB, VregB);
        pk1[1] = pk2u(0.0f, 1.0f);
        pkxB[wave][lane] = pk1;
    }

    const float rho   = rhop[0];
    const float rho_c = sqrtf(1.0f - rho * rho);
    const size_t estep = (size_t)N_SIM * D_OPT;
    const float* z1p = Z1  + (size_t)ebase + (size_t)lane;
    const float* z2p = Z2r + (size_t)ebase + (size_t)lane;

    float z1cA = z1p[0], z1cB = z1p[64];
    float z2cA = z2p[0], z2cB = z2p[64];
    z1p += estep; z2p += estep;

    __syncthreads();              // publish initial pkx
    LADDER(pkxA[wave], nvpA[wave]);   // ladder_A(0)
    LBAR();

    #pragma unroll 1
    for (int s = 0; s < M_STEPS; ++s) {
        // prefetch next-step z (both sets; stays in flight across barriers)
        const float z1nA = z1p[0], z1nB = z1p[64];
        const float z2nA = z2p[0], z2nB = z2p[64];
        const size_t adv = (s < M_STEPS - 2) ? estep : (size_t)0;
        z1p += adv; z2p += adv;

        // segment 1: MFMA ladder for B(s)  ||  trans/VALU update for A(s)
        LADDER(pkxB[wave], nvpB[wave]);
        UPDATE(nvpA, SregA, VregA, z1cA, z2cA, z1nA, z2nA, dtA, sdtA,
               pkxA[wave], s + 1);
        LBAR();

        // segment 2: MFMA ladder for A(s+1)  ||  update for B(s)
        if (s + 1 < M_STEPS)
            LADDER(pkxA[wave], nvpA[wave]);
        UPDATE(nvpB, SregB, VregB, z1cB, z2cB, z1nB, z2nB, dtB, sdtB,
               pkxB[wave], s + 1);
        LBAR();
    }

    // ---- payoff: wave 0, lane == element ----
    if (wave == 0) {
        const float TdA = dtA * (float)M_STEPS;
        const float pA  = fmaxf(SregA - Kp[dA_], 0.0f);
        atomicAdd(&out[dA_], __expf(-rf * TdA) * pA * (1.0f / (float)N_SIM));
        const float TdB = dtB * (float)M_STEPS;
        const float pB  = fmaxf(SregB - Kp[dB_], 0.0f);
        atomicAdd(&out[dB_], __expf(-rf * TdB) * pB * (1.0f / (float)N_SIM));
    }
}

extern "C" void kernel_launch(void* const* d_in, const int* in_sizes, int n_in,
                              void* d_out, int out_size, void* d_ws, size_t ws_size,
                              hipStream_t stream)
{
    const float* S0  = (const float*)d_in[0];
    const float* K   = (const float*)d_in[1];
    const float* T   = (const float*)d_in[2];
    const float* rf  = (const float*)d_in[3];
    const float* V0  = (const float*)d_in[4];
    const float* rho = (const float*)d_in[5];
    const float* Z1  = (const float*)d_in[6];
    const float* Z2r = (const float*)d_in[7];
    const float* W1  = (const float*)d_in[8];
    const float* B1  = (const float*)d_in[9];
    const float* W2  = (const float*)d_in[10];
    const float* B2  = (const float*)d_in[11];
    const float* W3  = (const float*)d_in[12];
    const float* B3  = (const float*)d_in[13];
    float* out = (float*)d_out;

    hipMemsetAsync(out, 0, (size_t)out_size * sizeof(float), stream);

    const int total = N_SIM * D_OPT;              // 262144 elements
    const int grid  = total / 128;                // 128 elements per block
    nsde_kernel<<<grid, 256, 0, stream>>>(S0, K, T, rf, V0, rho, Z1, Z2r,
                                          W1, B1, W2, B2, W3, B3, out);
}